// Round 1
// 180.565 us; speedup vs baseline: 1.0084x; 1.0084x over previous
//
#include <hip/hip_runtime.h>

// Problem constants (from reference): N=8, H=512, W=512, K=1, NF=100000, D=8
#define NN 8
#define HH 512
#define WW 512
#define DD 8

constexpr int HW   = HH * WW;        // 262144 (pow2)
constexpr int NPIX = NN * HW;        // 2,097,152
constexpr int BLK  = 256;            // block size; 4 independent waves
constexpr int CST  = 66;             // per-wave chunk stride (64 px + 2 pad)
// Bank-group math (32 banks, b128 ops -> 8 groups of 4 banks):
//   write lane (p,c): group = (2c + p) & 7  -> uniform over 64 lanes (min cycles)
//   read  lane, c fixed: group = (2c + lane) & 7 -> uniform (conflict-free)

typedef float v4f __attribute__((ext_vector_type(4)));

// Each face row in attr is 24 floats = 96 B = 6 x float4 "chunks".
// Wave-local cooperative gather: work-item w = p*6+c distributed over the
// wave's 64 lanes so consecutive lanes load consecutive chunks of the SAME
// face (~1.5 line-requests/face). Face ids move lane->lane via __shfl and
// chunks transpose through a PER-WAVE LDS region, so NO __syncthreads is
// needed anywhere: waves issue and retire fully independently (no block-wide
// vmcnt drain at a barrier).
__global__ __launch_bounds__(256) void interp_wave(
    const int*   __restrict__ p2f,   // [N*H*W] packed face index, -1 = empty
    const float* __restrict__ bary,  // [N*H*W, 3] (rows sum to 1)
    const float* __restrict__ attr,  // [N*NF, 3, D] -> 6 float4 per face
    float*       __restrict__ out)   // [N, D+1, H, W]
{
    __shared__ v4f chunks[BLK / 64][6][CST];   // 4 x 6 x 66 x 16 B = 25,344 B

    const int t    = threadIdx.x;
    const int lane = t & 63;
    const int wv   = t >> 6;
    const int i    = blockIdx.x * BLK + t;     // this thread's pixel

    // --- per-pixel stream loads (single-use: NT hint keeps them out of L2's
    //     way so attr lines survive longer) ---
    const int  f     = __builtin_nontemporal_load(p2f + i);
    const bool valid = f >= 0;
    const int  fc    = valid ? f : 0;

    const size_t bi = (size_t)i * 3;
    float b0 = __builtin_nontemporal_load(bary + bi + 0);
    float b1 = __builtin_nontemporal_load(bary + bi + 1);
    float b2 = 1.0f - b0 - b1;                 // rows sum to 1 (err ~1e-7)
    if (!valid) { b0 = 0.0f; b1 = 0.0f; b2 = 0.0f; }

    const v4f* ap = (const v4f*)attr;
    v4f (*ch)[CST] = chunks[wv];               // this wave's private region

    // --- wave-local coalesced gather: 384 chunk-loads in 6 rounds ---
    #pragma unroll
    for (int j = 0; j < 6; ++j) {
        const int w  = j * 64 + lane;          // consecutive lanes -> consecutive (p,c)
        const int p  = w / 6;                  // pixel within wave [0,64)
        const int c  = w - p * 6;              // chunk within face [0,6)
        const int ff = __shfl(fc, p, 64);      // face id from owning lane
        ch[c][p] = ap[(size_t)ff * 6 + c];
    }

    // Intra-wave producer/consumer: compiler-inserted lgkmcnt ordering is
    // sufficient — no barrier.
    const v4f x0 = ch[0][lane];                // vert0 ch0-3
    const v4f x1 = ch[1][lane];                // vert0 ch4-7
    const v4f y0 = ch[2][lane];
    const v4f y1 = ch[3][lane];
    const v4f z0 = ch[4][lane];
    const v4f z1 = ch[5][lane];

    const v4f lo = b0 * x0 + b1 * y0 + b2 * z0;   // ch0-3
    const v4f hi = b0 * x1 + b1 * y1 + b2 * z1;   // ch4-7

    // --- planar output [N, D+1, H, W], coalesced per plane ---
    const int n   = i >> 18;                   // i / HW
    const int pix = i & (HW - 1);              // i % HW
    float* ob = out + (size_t)n * (DD + 1) * HW + pix;

    __builtin_nontemporal_store(lo.x, ob + 0 * (size_t)HW);
    __builtin_nontemporal_store(lo.y, ob + 1 * (size_t)HW);
    __builtin_nontemporal_store(lo.z, ob + 2 * (size_t)HW);
    __builtin_nontemporal_store(lo.w, ob + 3 * (size_t)HW);
    __builtin_nontemporal_store(hi.x, ob + 4 * (size_t)HW);
    __builtin_nontemporal_store(hi.y, ob + 5 * (size_t)HW);
    __builtin_nontemporal_store(hi.z, ob + 6 * (size_t)HW);
    __builtin_nontemporal_store(hi.w, ob + 7 * (size_t)HW);
    __builtin_nontemporal_store(valid ? 1.0f : 0.0f, ob + 8 * (size_t)HW);
}

extern "C" void kernel_launch(void* const* d_in, const int* in_sizes, int n_in,
                              void* d_out, int out_size, void* d_ws, size_t ws_size,
                              hipStream_t stream) {
    const int*   p2f  = (const int*)d_in[0];
    const float* bary = (const float*)d_in[1];
    const float* attr = (const float*)d_in[2];
    float*       out  = (float*)d_out;

    const int grid = NPIX / BLK;               // 8192 blocks
    interp_wave<<<grid, BLK, 0, stream>>>(p2f, bary, attr, out);
}

// Round 2
// 180.240 us; speedup vs baseline: 1.0102x; 1.0018x over previous
//
#include <hip/hip_runtime.h>

// Problem constants (from reference): N=8, H=512, W=512, K=1, NF=100000, D=8
#define NN 8
#define HH 512
#define WW 512
#define DD 8

constexpr int HW   = HH * WW;        // 262144 (pow2)
constexpr int NPIX = NN * HW;        // 2,097,152
constexpr int BLK  = 256;            // 4 independent waves per block
constexpr int FST  = 33;             // 32 faces + 1 pad chunk (odd stride)
// Bank-group math (32 banks, b128 ops -> 8 groups of 4 banks), stride 33:
//   chunk index m = c*33 + p  ->  group = (c + p) & 7
//   write lanes (w=p*6+c):  p fixed, c=0..5 -> 6 consecutive groups (uniform)
//   read  lanes (c fixed):  group = (c + lane) & 7 -> exactly uniform

typedef float v4f __attribute__((ext_vector_type(4)));

// Each face row in attr is 24 floats = 96 B = 6 x float4 "chunks".
// Wave-local cooperative gather (consecutive lanes -> consecutive chunks of
// the SAME face, ~1.5 line-requests/face) with a TWO-BATCH transpose:
// work item w = p*6+c means rounds 0-2 hold exactly all chunks of pixels
// p<32 and rounds 3-5 all chunks of p>=32. One 6x32-chunk buffer per wave is
// written twice (slot = p&31), halving LDS (25.6 -> 12.7 KB/block) so the
// occupancy cap rises from 24 to 32 waves/CU. All 6 gather loads still issue
// up-front for full memory-level parallelism. No __syncthreads anywhere;
// intra-wave DS ordering (in-order DS pipe) makes batch-A reads complete
// before batch-B overwrites.
__global__ __launch_bounds__(256, 8) void interp_wave_split(
    const int*   __restrict__ p2f,   // [N*H*W] packed face index, -1 = empty
    const float* __restrict__ bary,  // [N*H*W, 3] (rows sum to 1)
    const float* __restrict__ attr,  // [N*NF, 3, D] -> 6 float4 per face
    float*       __restrict__ out)   // [N, D+1, H, W]
{
    __shared__ v4f chunks[BLK / 64][6 * FST];   // 4 x 198 x 16 B = 12,672 B

    const int t    = threadIdx.x;
    const int lane = t & 63;
    const int wv   = t >> 6;
    const int i    = blockIdx.x * BLK + t;      // this thread's pixel

    // --- per-pixel stream loads (single-use: NT keeps L2 for attr) ---
    const int  f     = __builtin_nontemporal_load(p2f + i);
    const bool valid = f >= 0;
    const int  fc    = valid ? f : 0;

    const size_t bi = (size_t)i * 3;
    float b0 = __builtin_nontemporal_load(bary + bi + 0);
    float b1 = __builtin_nontemporal_load(bary + bi + 1);
    float b2 = 1.0f - b0 - b1;                  // rows sum to 1 (err ~1e-7)
    if (!valid) { b0 = 0.0f; b1 = 0.0f; b2 = 0.0f; }

    const v4f* ap = (const v4f*)attr;
    v4f* ch = chunks[wv];                       // this wave's private region

    // --- issue all 6 gather loads up-front (max MLP per wave) ---
    int wadr[6];
    v4f L[6];
    #pragma unroll
    for (int j = 0; j < 6; ++j) {
        const int w  = j * 64 + lane;           // consecutive lanes -> consecutive (p,c)
        const int p  = w / 6;                   // pixel within wave [0,64)
        const int c  = w - p * 6;               // chunk within face [0,6)
        const int ff = __shfl(fc, p, 64);       // face id from owning lane
        wadr[j] = c * FST + (p & 31);           // slot reused by both batches
        L[j] = ap[(size_t)ff * 6 + c];
    }

    // --- planar output [N, D+1, H, W], coalesced per plane ---
    const int n   = i >> 18;                    // i / HW
    const int pix = i & (HW - 1);               // i % HW
    float* ob = out + (size_t)n * (DD + 1) * HW + pix;

    auto blendStore = [&](int slot) {
        const v4f x0 = ch[0 * FST + slot];      // vert0 ch0-3
        const v4f x1 = ch[1 * FST + slot];      // vert0 ch4-7
        const v4f y0 = ch[2 * FST + slot];
        const v4f y1 = ch[3 * FST + slot];
        const v4f z0 = ch[4 * FST + slot];
        const v4f z1 = ch[5 * FST + slot];
        const v4f lo = b0 * x0 + b1 * y0 + b2 * z0;   // ch0-3
        const v4f hi = b0 * x1 + b1 * y1 + b2 * z1;   // ch4-7
        __builtin_nontemporal_store(lo.x, ob + 0 * (size_t)HW);
        __builtin_nontemporal_store(lo.y, ob + 1 * (size_t)HW);
        __builtin_nontemporal_store(lo.z, ob + 2 * (size_t)HW);
        __builtin_nontemporal_store(lo.w, ob + 3 * (size_t)HW);
        __builtin_nontemporal_store(hi.x, ob + 4 * (size_t)HW);
        __builtin_nontemporal_store(hi.y, ob + 5 * (size_t)HW);
        __builtin_nontemporal_store(hi.z, ob + 6 * (size_t)HW);
        __builtin_nontemporal_store(hi.w, ob + 7 * (size_t)HW);
        __builtin_nontemporal_store(valid ? 1.0f : 0.0f, ob + 8 * (size_t)HW);
    };

    // --- batch A: rounds 0-2 complete pixels [0,32) ---
    #pragma unroll
    for (int j = 0; j < 3; ++j) ch[wadr[j]] = L[j];
    if (lane < 32) blendStore(lane);

    // --- batch B: rounds 3-5 complete pixels [32,64), reusing the slots ---
    #pragma unroll
    for (int j = 3; j < 6; ++j) ch[wadr[j]] = L[j];
    if (lane >= 32) blendStore(lane - 32);
}

extern "C" void kernel_launch(void* const* d_in, const int* in_sizes, int n_in,
                              void* d_out, int out_size, void* d_ws, size_t ws_size,
                              hipStream_t stream) {
    const int*   p2f  = (const int*)d_in[0];
    const float* bary = (const float*)d_in[1];
    const float* attr = (const float*)d_in[2];
    float*       out  = (float*)d_out;

    const int grid = NPIX / BLK;               // 8192 blocks
    interp_wave_split<<<grid, BLK, 0, stream>>>(p2f, bary, attr, out);
}